// Round 1
// baseline (1176.706 us; speedup 1.0000x reference)
//
#include <hip/hip_runtime.h>

#define N_NODES  50000
#define N_EDGES  1600000
#define IN_CH    128
#define EDGE_DIM 32
#define AGG_DIM  160   // IN_CH + EDGE_DIM
#define OUT_CH   128

// ---------------------------------------------------------------------------
// Phase 1: one wave (64 lanes) per edge.
//   lane i      -> agg[row][i]      += norm * x[col][i]
//   lane i      -> agg[row][i+64]   += norm * x[col][i+64]
//   lane i<32   -> agg[row][128+i]  += norm * edge_attr[e][i]
// Gathers from x are coalesced (consecutive channels per row); atomics to agg
// are coalesced per edge-row. row/col/norm are wave-uniform scalar loads.
// ---------------------------------------------------------------------------
__global__ __launch_bounds__(256) void scatter_kernel(
    const float* __restrict__ x,
    const int*   __restrict__ row,
    const int*   __restrict__ col,
    const float* __restrict__ norm,
    const float* __restrict__ ea,
    float*       __restrict__ agg)
{
    const int wave = (blockIdx.x * blockDim.x + threadIdx.x) >> 6;
    const int lane = threadIdx.x & 63;
    if (wave >= N_EDGES) return;

    const int   r  = row[wave];
    const int   c  = col[wave];
    const float nv = norm[wave];

    const float* xr = x + (size_t)c * IN_CH;
    float*       ar = agg + (size_t)r * AGG_DIM;

    atomicAdd(ar + lane,      nv * xr[lane]);
    atomicAdd(ar + lane + 64, nv * xr[lane + 64]);
    if (lane < EDGE_DIM) {
        atomicAdd(ar + IN_CH + lane, nv * ea[(size_t)wave * EDGE_DIM + lane]);
    }
}

// ---------------------------------------------------------------------------
// Phase 2: out[n][c] = sum_k agg[n][k] * W[k][c] + b[c]
// Block of 256 threads handles 2 nodes x 128 channels. agg rows staged in LDS
// (broadcast reads, conflict-free). W column reads are coalesced across lanes
// and hot in L1/L2 (80 KB total).
// ---------------------------------------------------------------------------
__global__ __launch_bounds__(256) void gemm_kernel(
    const float* __restrict__ agg,
    const float* __restrict__ W,
    const float* __restrict__ b,
    float*       __restrict__ out)
{
    __shared__ float aS[2][AGG_DIM];
    const int node0 = blockIdx.x * 2;
    const int tid   = threadIdx.x;

    for (int i = tid; i < 2 * AGG_DIM; i += 256) {
        const int n    = i / AGG_DIM;
        const int k    = i % AGG_DIM;
        const int node = node0 + n;
        aS[n][k] = (node < N_NODES) ? agg[(size_t)node * AGG_DIM + k] : 0.0f;
    }
    __syncthreads();

    const int n    = tid >> 7;     // 0 or 1
    const int cch  = tid & 127;
    const int node = node0 + n;
    if (node >= N_NODES) return;

    float acc = b[cch];
#pragma unroll 8
    for (int k = 0; k < AGG_DIM; ++k) {
        acc += aS[n][k] * W[k * OUT_CH + cch];
    }
    out[(size_t)node * OUT_CH + cch] = acc;
}

extern "C" void kernel_launch(void* const* d_in, const int* in_sizes, int n_in,
                              void* d_out, int out_size, void* d_ws, size_t ws_size,
                              hipStream_t stream)
{
    const float* x    = (const float*)d_in[0];
    const int*   row  = (const int*)  d_in[1];
    const int*   col  = (const int*)  d_in[2];
    const float* norm = (const float*)d_in[3];
    const float* ea   = (const float*)d_in[4];
    const float* W    = (const float*)d_in[5];
    const float* b    = (const float*)d_in[6];
    float*       out  = (float*)d_out;

    float* agg = (float*)d_ws;   // [N_NODES, AGG_DIM] fp32 = 32 MB

    // Workspace is poisoned with 0xAA before every launch — zero it.
    hipMemsetAsync(agg, 0, (size_t)N_NODES * AGG_DIM * sizeof(float), stream);

    // Phase 1: one wave per edge; 4 waves per 256-thread block.
    {
        const int wavesPerBlock = 256 / 64;
        const int grid = (N_EDGES + wavesPerBlock - 1) / wavesPerBlock;
        scatter_kernel<<<grid, 256, 0, stream>>>(x, row, col, norm, ea, agg);
    }

    // Phase 2: dense GEMM, 2 nodes per block.
    {
        const int grid = (N_NODES + 1) / 2;
        gemm_kernel<<<grid, 256, 0, stream>>>(agg, W, b, out);
    }
}

// Round 2
// 988.407 us; speedup vs baseline: 1.1905x; 1.1905x over previous
//
#include <hip/hip_runtime.h>

#define N_NODES  50000
#define N_EDGES  1600000
#define IN_CH    128
#define EDGE_DIM 32
#define AGG_DIM  160   // IN_CH + EDGE_DIM
#define OUT_CH   128

// ---------------------------------------------------------------------------
// Pass A: per-node degree histogram. 1.6M int atomics over 200 KB (L2-hot).
// ---------------------------------------------------------------------------
__global__ __launch_bounds__(256) void hist_kernel(
    const int* __restrict__ row, int* __restrict__ counts)
{
    const int e = blockIdx.x * 256 + threadIdx.x;
    if (e < N_EDGES) atomicAdd(&counts[row[e]], 1);
}

// ---------------------------------------------------------------------------
// Pass B: exclusive scan of counts -> ptr[0..N_NODES].
// Single block, 1024 threads = 16 waves; shuffle scan within wave, LDS scan
// across waves, register-held running carry (identical in all threads).
// ---------------------------------------------------------------------------
__global__ __launch_bounds__(1024) void scan_kernel(
    const int* __restrict__ counts, int* __restrict__ ptr)
{
    __shared__ int waveTot[16];
    __shared__ int waveInc[16];
    const int tid  = threadIdx.x;
    const int lane = tid & 63;
    const int wid  = tid >> 6;

    int carry = 0;
    for (int base = 0; base < N_NODES; base += 1024) {
        const int i = base + tid;
        const int v = (i < N_NODES) ? counts[i] : 0;

        // inclusive scan within wave
        int s = v;
        #pragma unroll
        for (int off = 1; off < 64; off <<= 1) {
            int t = __shfl_up(s, off, 64);
            if (lane >= off) s += t;
        }
        if (lane == 63) waveTot[wid] = s;
        __syncthreads();

        // wave 0 scans the 16 wave totals
        if (wid == 0) {
            int t = (lane < 16) ? waveTot[lane] : 0;
            #pragma unroll
            for (int off = 1; off < 16; off <<= 1) {
                int u = __shfl_up(t, off, 64);
                if (lane >= off) t += u;
            }
            if (lane < 16) waveInc[lane] = t;
        }
        __syncthreads();

        const int waveExcl = (wid == 0) ? 0 : waveInc[wid - 1];
        const int incl     = carry + waveExcl + s;
        if (i < N_NODES) ptr[i] = incl - v;   // exclusive
        carry += waveInc[15];
        __syncthreads();   // protect waveTot/waveInc before next chunk
    }
    if (tid == 0) ptr[N_NODES] = carry;   // == N_EDGES
}

// ---------------------------------------------------------------------------
// Pass C: scatter edge payloads into CSR slots. Destructive on ptr: after this
// kernel, ptr[n] == original ptr[n+1], so node n's segment is
// [n>0 ? ptr[n-1] : 0, ptr[n]).
// ---------------------------------------------------------------------------
__global__ __launch_bounds__(256) void csr_build_kernel(
    const int* __restrict__ row, const int* __restrict__ col,
    const float* __restrict__ norm,
    int* __restrict__ ptr,
    int* __restrict__ csr_col, float* __restrict__ csr_norm,
    int* __restrict__ csr_eid)
{
    const int e = blockIdx.x * 256 + threadIdx.x;
    if (e >= N_EDGES) return;
    const int r   = row[e];
    const int pos = atomicAdd(&ptr[r], 1);
    csr_col[pos]  = col[e];
    csr_norm[pos] = norm[e];
    csr_eid[pos]  = e;
}

// ---------------------------------------------------------------------------
// Pass D: fused gather + GEMM. One wave per node (4 nodes / 256-thr block).
// Gather: lane holds channels {2*lane, 2*lane+1} of the x-part (float2 loads:
// one 512 B wave-transaction per edge) and lanes<16 hold the 32 edge_attr
// channels. Zero atomics; agg row staged through 640 B of LDS; GEMM reads W
// as float2 (L1/L2-hot, same addresses across all waves).
// ---------------------------------------------------------------------------
__global__ __launch_bounds__(256) void gather_gemm_kernel(
    const float* __restrict__ x,
    const float* __restrict__ ea,
    const int*   __restrict__ ptr,
    const int*   __restrict__ csr_col,
    const float* __restrict__ csr_norm,
    const int*   __restrict__ csr_eid,
    const float* __restrict__ W,
    const float* __restrict__ b,
    float*       __restrict__ out)
{
    __shared__ float aggS[4][AGG_DIM];
    const int w    = threadIdx.x >> 6;
    const int lane = threadIdx.x & 63;
    const int n    = blockIdx.x * 4 + w;   // grid*4 == N_NODES exactly

    const int start = (n > 0) ? ptr[n - 1] : 0;
    const int end   = ptr[n];

    float2 a0 = make_float2(0.f, 0.f);   // x-part channels 2*lane, 2*lane+1
    float2 a2 = make_float2(0.f, 0.f);   // ea channels 2*lane, 2*lane+1 (lane<16)

    #pragma unroll 2
    for (int e = start; e < end; ++e) {
        const int    c  = csr_col[e];
        const float  nv = csr_norm[e];
        const float2 xv = ((const float2*)(x + (size_t)c * IN_CH))[lane];
        a0.x += nv * xv.x;
        a0.y += nv * xv.y;
        if (lane < 16) {
            const int    eid = csr_eid[e];
            const float2 ev  = ((const float2*)(ea + (size_t)eid * EDGE_DIM))[lane];
            a2.x += nv * ev.x;
            a2.y += nv * ev.y;
        }
    }

    ((float2*)aggS[w])[lane] = a0;
    if (lane < 16) ((float2*)(aggS[w] + IN_CH))[lane] = a2;
    __syncthreads();   // cheap; all waves reach it (no early returns)

    // out channels 2*lane, 2*lane+1
    float2 acc = ((const float2*)b)[lane];
    #pragma unroll 8
    for (int k = 0; k < AGG_DIM; ++k) {
        const float  av = aggS[w][k];
        const float2 wv = ((const float2*)(W + k * OUT_CH))[lane];
        acc.x += av * wv.x;
        acc.y += av * wv.y;
    }
    ((float2*)(out + (size_t)n * OUT_CH))[lane] = acc;
}

extern "C" void kernel_launch(void* const* d_in, const int* in_sizes, int n_in,
                              void* d_out, int out_size, void* d_ws, size_t ws_size,
                              hipStream_t stream)
{
    const float* x    = (const float*)d_in[0];
    const int*   row  = (const int*)  d_in[1];
    const int*   col  = (const int*)  d_in[2];
    const float* norm = (const float*)d_in[3];
    const float* ea   = (const float*)d_in[4];
    const float* W    = (const float*)d_in[5];
    const float* b    = (const float*)d_in[6];
    float*       out  = (float*)d_out;

    // Workspace layout (all 256-byte aligned; total ~19.6 MB < ws_size)
    char* ws = (char*)d_ws;
    int*   counts   = (int*)  (ws + 0);          // 50000 ints
    int*   ptr      = (int*)  (ws + 200192);     // 50001 ints
    int*   csr_col  = (int*)  (ws + 400384);     // 1.6M ints
    float* csr_norm = (float*)(ws + 6800384);    // 1.6M floats
    int*   csr_eid  = (int*)  (ws + 13200384);   // 1.6M ints

    // ws is re-poisoned to 0xAA before every launch: zero the histogram.
    hipMemsetAsync(counts, 0, (size_t)N_NODES * sizeof(int), stream);

    hist_kernel<<<(N_EDGES + 255) / 256, 256, 0, stream>>>(row, counts);
    scan_kernel<<<1, 1024, 0, stream>>>(counts, ptr);
    csr_build_kernel<<<(N_EDGES + 255) / 256, 256, 0, stream>>>(
        row, col, norm, ptr, csr_col, csr_norm, csr_eid);
    gather_gemm_kernel<<<N_NODES / 4, 256, 0, stream>>>(
        x, ea, ptr, csr_col, csr_norm, csr_eid, W, b, out);
}

// Round 3
// 847.475 us; speedup vs baseline: 1.3885x; 1.1663x over previous
//
#include <hip/hip_runtime.h>

#define N_NODES  50000
#define N_EDGES  1600000
#define IN_CH    128
#define EDGE_DIM 32
#define AGG_DIM  160   // IN_CH + EDGE_DIM
#define OUT_CH   128

typedef float f32x4 __attribute__((ext_vector_type(4)));
typedef float f32x2 __attribute__((ext_vector_type(2)));
typedef int   i32x4 __attribute__((ext_vector_type(4)));

// ---------------------------------------------------------------------------
// Pass A: per-node degree histogram.
// ---------------------------------------------------------------------------
__global__ __launch_bounds__(256) void hist_kernel(
    const int* __restrict__ row, int* __restrict__ counts)
{
    const int e = blockIdx.x * 256 + threadIdx.x;
    if (e < N_EDGES) atomicAdd(&counts[row[e]], 1);
}

// ---------------------------------------------------------------------------
// Pass B: exclusive scan of counts -> ptr[0..N_NODES-1]. (unchanged, verified)
// ---------------------------------------------------------------------------
__global__ __launch_bounds__(1024) void scan_kernel(
    const int* __restrict__ counts, int* __restrict__ ptr)
{
    __shared__ int waveTot[16];
    __shared__ int waveInc[16];
    const int tid  = threadIdx.x;
    const int lane = tid & 63;
    const int wid  = tid >> 6;

    int carry = 0;
    for (int base = 0; base < N_NODES; base += 1024) {
        const int i = base + tid;
        const int v = (i < N_NODES) ? counts[i] : 0;

        int s = v;
        #pragma unroll
        for (int off = 1; off < 64; off <<= 1) {
            int t = __shfl_up(s, off, 64);
            if (lane >= off) s += t;
        }
        if (lane == 63) waveTot[wid] = s;
        __syncthreads();

        if (wid == 0) {
            int t = (lane < 16) ? waveTot[lane] : 0;
            #pragma unroll
            for (int off = 1; off < 16; off <<= 1) {
                int u = __shfl_up(t, off, 64);
                if (lane >= off) t += u;
            }
            if (lane < 16) waveInc[lane] = t;
        }
        __syncthreads();

        const int waveExcl = (wid == 0) ? 0 : waveInc[wid - 1];
        const int incl     = carry + waveExcl + s;
        if (i < N_NODES) ptr[i] = incl - v;
        carry += waveInc[15];
        __syncthreads();
    }
}

// ---------------------------------------------------------------------------
// Pass C: scatter packed edge payload (col, norm, eid, 0) into CSR slots.
// One 16-B store per edge (vs 3 scattered 4-B stores before).
// Destructive on ptr: after this, ptr[n] == original ptr[n+1].
// ---------------------------------------------------------------------------
__global__ __launch_bounds__(256) void csr_build_kernel(
    const int* __restrict__ row, const int* __restrict__ col,
    const float* __restrict__ norm,
    int* __restrict__ ptr,
    i32x4* __restrict__ csr)
{
    const int e = blockIdx.x * 256 + threadIdx.x;
    if (e >= N_EDGES) return;
    const int r   = row[e];
    const int pos = atomicAdd(&ptr[r], 1);
    i32x4 p;
    p.x = col[e];
    p.y = __float_as_int(norm[e]);
    p.z = e;
    p.w = 0;
    csr[pos] = p;
}

// ---------------------------------------------------------------------------
// Pass D: fused gather + GEMM. One WAVE per node, one HALF-WAVE (32 lanes)
// per edge, unrolled x2 => 4 independent edge gathers in flight.
//   half h (lanes 32h..32h+31) handles edges e+h, e+2+h of node n.
//   lane hl<32 loads x[col][4*hl..4*hl+3] as float4 (512 B/row per half-wave).
//   lanes hl<8 load the edge's 32 edge_attr channels as float4.
// Even/odd-edge partials combined with __shfl_xor(32). Zero atomics.
// ---------------------------------------------------------------------------
__global__ __launch_bounds__(256) void gather_gemm_kernel(
    const float* __restrict__ x,
    const float* __restrict__ ea,
    const int*   __restrict__ ptr,
    const i32x4* __restrict__ csr,
    const float* __restrict__ W,
    const float* __restrict__ b,
    float*       __restrict__ out)
{
    __shared__ float aggS[4][AGG_DIM];
    const int w    = threadIdx.x >> 6;
    const int lane = threadIdx.x & 63;
    const int half = lane >> 5;     // 0 or 1: which edge of the pair
    const int hl   = lane & 31;     // lane within half-wave
    const int n    = blockIdx.x * 4 + w;   // grid*4 == N_NODES exactly

    const int start = (n > 0) ? ptr[n - 1] : 0;
    const int end   = ptr[n];

    f32x4 accx = {0.f, 0.f, 0.f, 0.f};
    f32x4 acce = {0.f, 0.f, 0.f, 0.f};

    int e = start;
    // main loop: 4 edges per iteration (2 per half-wave), all loads independent
    for (; e + 4 <= end; e += 4) {
        const i32x4 pA = __builtin_nontemporal_load(&csr[e + half]);
        const i32x4 pB = __builtin_nontemporal_load(&csr[e + 2 + half]);
        const float nA = __int_as_float(pA.y);
        const float nB = __int_as_float(pB.y);
        const f32x4 xA = ((const f32x4*)(x + (size_t)pA.x * IN_CH))[hl];
        const f32x4 xB = ((const f32x4*)(x + (size_t)pB.x * IN_CH))[hl];
        accx += nA * xA;
        accx += nB * xB;
        if (hl < 8) {
            const f32x4 eA = __builtin_nontemporal_load(
                (const f32x4*)(ea + (size_t)pA.z * EDGE_DIM) + hl);
            const f32x4 eB = __builtin_nontemporal_load(
                (const f32x4*)(ea + (size_t)pB.z * EDGE_DIM) + hl);
            acce += nA * eA;
            acce += nB * eB;
        }
    }
    // remainder: up to 3 edges, 2 per pass
    for (; e < end; e += 2) {
        const int eA = e + half;
        if (eA < end) {
            const i32x4 pA = __builtin_nontemporal_load(&csr[eA]);
            const float nA = __int_as_float(pA.y);
            const f32x4 xA = ((const f32x4*)(x + (size_t)pA.x * IN_CH))[hl];
            accx += nA * xA;
            if (hl < 8) {
                const f32x4 eAv = __builtin_nontemporal_load(
                    (const f32x4*)(ea + (size_t)pA.z * EDGE_DIM) + hl);
                acce += nA * eAv;
            }
        }
    }

    // combine even-edge (half 0) and odd-edge (half 1) partials
    #pragma unroll
    for (int i = 0; i < 4; ++i) {
        accx[i] += __shfl_xor(accx[i], 32, 64);
        acce[i] += __shfl_xor(acce[i], 32, 64);
    }
    if (half == 0) {
        ((f32x4*)aggS[w])[hl] = accx;
        if (hl < 8) ((f32x4*)(aggS[w] + IN_CH))[hl] = acce;
    }
    __syncthreads();   // all waves reach this (no early returns)

    // GEMM: out channels 2*lane, 2*lane+1
    f32x2 acc = ((const f32x2*)b)[lane];
    #pragma unroll 8
    for (int k = 0; k < AGG_DIM; ++k) {
        const float av = aggS[w][k];
        const f32x2 wv = ((const f32x2*)(W + k * OUT_CH))[lane];
        acc.x += av * wv.x;
        acc.y += av * wv.y;
    }
    ((f32x2*)(out + (size_t)n * OUT_CH))[lane] = acc;
}

extern "C" void kernel_launch(void* const* d_in, const int* in_sizes, int n_in,
                              void* d_out, int out_size, void* d_ws, size_t ws_size,
                              hipStream_t stream)
{
    const float* x    = (const float*)d_in[0];
    const int*   row  = (const int*)  d_in[1];
    const int*   col  = (const int*)  d_in[2];
    const float* norm = (const float*)d_in[3];
    const float* ea   = (const float*)d_in[4];
    const float* W    = (const float*)d_in[5];
    const float* b    = (const float*)d_in[6];
    float*       out  = (float*)d_out;

    // Workspace layout: counts @ 0 (200 KB), ptr @ 256 KB (200 KB),
    // packed csr @ 512 KB (1.6M x 16 B = 25.6 MB). Total ~26.1 MB.
    char*  ws     = (char*)d_ws;
    int*   counts = (int*)  (ws + 0);
    int*   ptr    = (int*)  (ws + (1 << 18));
    i32x4* csr    = (i32x4*)(ws + (1 << 19));

    hipMemsetAsync(counts, 0, (size_t)N_NODES * sizeof(int), stream);

    hist_kernel<<<(N_EDGES + 255) / 256, 256, 0, stream>>>(row, counts);
    scan_kernel<<<1, 1024, 0, stream>>>(counts, ptr);
    csr_build_kernel<<<(N_EDGES + 255) / 256, 256, 0, stream>>>(
        row, col, norm, ptr, csr);
    gather_gemm_kernel<<<N_NODES / 4, 256, 0, stream>>>(
        x, ea, ptr, csr, W, b, out);
}

// Round 5
// 744.027 us; speedup vs baseline: 1.5815x; 1.1390x over previous
//
#include <hip/hip_runtime.h>

#define N_NODES  50000
#define N_EDGES  1600000
#define IN_CH    128
#define EDGE_DIM 32
#define AGG_DIM  160   // IN_CH + EDGE_DIM
#define OUT_CH   128
#define SCAN_BS  1024
#define NBLK     ((N_NODES + SCAN_BS - 1) / SCAN_BS)   // 49

typedef float f32x4 __attribute__((ext_vector_type(4)));
typedef float f32x2 __attribute__((ext_vector_type(2)));
typedef int   i32x4 __attribute__((ext_vector_type(4)));
typedef unsigned int u32x4 __attribute__((ext_vector_type(4)));
typedef unsigned int       uint32;
typedef unsigned long long uint64;
typedef unsigned short     ushort16;

__device__ __forceinline__ uint32 bf16rn(float f) {
    const uint32 u = __float_as_uint(f);
    return (u + 0x7FFFu + ((u >> 16) & 1u)) >> 16;   // round-to-nearest-even bf16 bits
}

// ---------------------------------------------------------------------------
// hist: per-node degree histogram.
// ---------------------------------------------------------------------------
__global__ __launch_bounds__(256) void hist_kernel(
    const int* __restrict__ row, int* __restrict__ counts)
{
    const int e = blockIdx.x * 256 + threadIdx.x;
    if (e < N_EDGES) atomicAdd(&counts[row[e]], 1);
}

// ---------------------------------------------------------------------------
// Multi-block exclusive scan: local per-block scan + block totals, then a
// single-wave scan of the 49 totals, then an add pass.
// ---------------------------------------------------------------------------
__global__ __launch_bounds__(1024) void scan_local_kernel(
    const int* __restrict__ counts, int* __restrict__ ptr, int* __restrict__ bsums)
{
    __shared__ int waveTot[16];
    __shared__ int waveInc[16];
    const int tid  = threadIdx.x;
    const int lane = tid & 63;
    const int wid  = tid >> 6;
    const int i    = blockIdx.x * SCAN_BS + tid;
    const int v    = (i < N_NODES) ? counts[i] : 0;

    int s = v;
    #pragma unroll
    for (int off = 1; off < 64; off <<= 1) {
        const int t = __shfl_up(s, off, 64);
        if (lane >= off) s += t;
    }
    if (lane == 63) waveTot[wid] = s;
    __syncthreads();
    if (wid == 0) {
        int t = (lane < 16) ? waveTot[lane] : 0;
        #pragma unroll
        for (int off = 1; off < 16; off <<= 1) {
            const int u = __shfl_up(t, off, 64);
            if (lane >= off) t += u;
        }
        if (lane < 16) waveInc[lane] = t;
    }
    __syncthreads();
    const int excl = ((wid == 0) ? 0 : waveInc[wid - 1]) + s - v;
    if (i < N_NODES) ptr[i] = excl;
    if (tid == 0) bsums[blockIdx.x] = waveInc[15];
}

__global__ __launch_bounds__(64) void scan_sums_kernel(
    const int* __restrict__ bsums, int* __restrict__ boff)
{
    const int lane = threadIdx.x;
    const int v = (lane < NBLK) ? bsums[lane] : 0;
    int s = v;
    #pragma unroll
    for (int off = 1; off < 64; off <<= 1) {
        const int t = __shfl_up(s, off, 64);
        if (lane >= off) s += t;
    }
    if (lane < NBLK) boff[lane] = s - v;
}

__global__ __launch_bounds__(256) void scan_add_kernel(
    int* __restrict__ ptr, const int* __restrict__ boff)
{
    const int i = blockIdx.x * 256 + threadIdx.x;
    if (i < N_NODES) ptr[i] += boff[i >> 10];
}

// ---------------------------------------------------------------------------
// cvt_x: x fp32 -> bf16 bits. 6.4M elements, 4 per thread.
// ---------------------------------------------------------------------------
__global__ __launch_bounds__(256) void cvt_x_kernel(
    const float* __restrict__ x, ushort16* __restrict__ xq)
{
    const int i = blockIdx.x * 256 + threadIdx.x;   // grid covers exactly N*IN_CH/4
    const f32x4 v = ((const f32x4*)x)[i];
    uint2 u;
    u.x = bf16rn(v.x) | (bf16rn(v.y) << 16);
    u.y = bf16rn(v.z) | (bf16rn(v.w) << 16);
    ((uint2*)xq)[i] = u;
}

// ---------------------------------------------------------------------------
// Tier A csr build: 8-B payload (col | norm<<32) + norm*ea as bf16 (64 B),
// both scattered to CSR position. ea read is streaming; NT stores keep L2
// free for x. Destructive on ptr (ptr[n] becomes segment end).
// ---------------------------------------------------------------------------
__global__ __launch_bounds__(256) void csr_build_a_kernel(
    const int* __restrict__ row, const int* __restrict__ col,
    const float* __restrict__ norm, const float* __restrict__ ea,
    int* __restrict__ ptr, uint64* __restrict__ csr, u32x4* __restrict__ eaq)
{
    const int e = blockIdx.x * 256 + threadIdx.x;
    if (e >= N_EDGES) return;
    const int   r  = row[e];
    const float nv = norm[e];
    const int  pos = atomicAdd(&ptr[r], 1);

    const uint64 p = ((uint64)__float_as_uint(nv) << 32) | (uint32)col[e];
    __builtin_nontemporal_store(p, csr + pos);

    const f32x4* src = (const f32x4*)(ea + (size_t)e * EDGE_DIM);
    u32x4* dst = eaq + (size_t)pos * 4;
    #pragma unroll
    for (int j = 0; j < 4; ++j) {
        const f32x4 a = src[2 * j];
        const f32x4 c = src[2 * j + 1];
        u32x4 u;
        u.x = bf16rn(nv * a.x) | (bf16rn(nv * a.y) << 16);
        u.y = bf16rn(nv * a.z) | (bf16rn(nv * a.w) << 16);
        u.z = bf16rn(nv * c.x) | (bf16rn(nv * c.y) << 16);
        u.w = bf16rn(nv * c.z) | (bf16rn(nv * c.w) << 16);
        __builtin_nontemporal_store(u, dst + j);
    }
}

// ---------------------------------------------------------------------------
// Tier A gather+GEMM. One wave per node; one QUARTER-wave (16 lanes) per
// edge, unrolled x2 => 8 independent edge gathers in flight.
//   lane ql<16 loads x_bf16[col][8*ql..8*ql+7] as u32x4 (256 B/row).
//   ea (pre-scaled bf16, CSR-sequential) read as 1 uint/lane (2 channels).
// Cross-quarter reduce via shfl_xor(16|32). Epilogue: each wave computes a
// 40-wide k-slice of the GEMM for ALL 4 nodes (W line fetched once serves 4
// nodes), partials reduced through LDS.
// ---------------------------------------------------------------------------
__global__ __launch_bounds__(256) void gather_gemm_a_kernel(
    const ushort16* __restrict__ xq,
    const uint64*   __restrict__ csr,
    const uint32*   __restrict__ eaq,
    const int*      __restrict__ ptr,
    const float*    __restrict__ W,
    const float*    __restrict__ b,
    float*          __restrict__ out)
{
    __shared__ float aggS[4][AGG_DIM];
    __shared__ f32x2 part[4][4][64];
    const int w    = threadIdx.x >> 6;
    const int lane = threadIdx.x & 63;
    const int q    = lane >> 4;
    const int ql   = lane & 15;
    const int n    = blockIdx.x * 4 + w;    // grid*4 == N_NODES exactly

    const int start = (n > 0) ? ptr[n - 1] : 0;
    const int end   = ptr[n];

    float ax[8] = {0, 0, 0, 0, 0, 0, 0, 0};
    float ae0 = 0.f, ae1 = 0.f;

    int e = start;
    for (; e + 8 <= end; e += 8) {
        const int sA = e + q;
        const int sB = e + 4 + q;
        const uint64 pA = __builtin_nontemporal_load(csr + sA);
        const uint64 pB = __builtin_nontemporal_load(csr + sB);
        const float  nA = __uint_as_float((uint32)(pA >> 32));
        const float  nB = __uint_as_float((uint32)(pB >> 32));
        const u32x4  xA = ((const u32x4*)(xq + (size_t)(uint32)(pA & 0xffffffffu) * IN_CH))[ql];
        const u32x4  xB = ((const u32x4*)(xq + (size_t)(uint32)(pB & 0xffffffffu) * IN_CH))[ql];
        const uint32 eA = __builtin_nontemporal_load(eaq + (size_t)sA * 16 + ql);
        const uint32 eB = __builtin_nontemporal_load(eaq + (size_t)sB * 16 + ql);

        #pragma unroll
        for (int j = 0; j < 4; ++j) {
            ax[2*j]   = fmaf(nA, __uint_as_float(xA[j] << 16),         ax[2*j]);
            ax[2*j+1] = fmaf(nA, __uint_as_float(xA[j] & 0xffff0000u), ax[2*j+1]);
            ax[2*j]   = fmaf(nB, __uint_as_float(xB[j] << 16),         ax[2*j]);
            ax[2*j+1] = fmaf(nB, __uint_as_float(xB[j] & 0xffff0000u), ax[2*j+1]);
        }
        ae0 += __uint_as_float(eA << 16);
        ae1 += __uint_as_float(eA & 0xffff0000u);
        ae0 += __uint_as_float(eB << 16);
        ae1 += __uint_as_float(eB & 0xffff0000u);
    }
    if (e < end) {                 // ragged tail, <=7 edges
        const int sA = e + q;
        if (sA < end) {
            const uint64 pA = __builtin_nontemporal_load(csr + sA);
            const float  nA = __uint_as_float((uint32)(pA >> 32));
            const u32x4  xA = ((const u32x4*)(xq + (size_t)(uint32)(pA & 0xffffffffu) * IN_CH))[ql];
            const uint32 eA = __builtin_nontemporal_load(eaq + (size_t)sA * 16 + ql);
            #pragma unroll
            for (int j = 0; j < 4; ++j) {
                ax[2*j]   = fmaf(nA, __uint_as_float(xA[j] << 16),         ax[2*j]);
                ax[2*j+1] = fmaf(nA, __uint_as_float(xA[j] & 0xffff0000u), ax[2*j+1]);
            }
            ae0 += __uint_as_float(eA << 16);
            ae1 += __uint_as_float(eA & 0xffff0000u);
        }
        const int sB = e + 4 + q;
        if (sB < end) {
            const uint64 pB = __builtin_nontemporal_load(csr + sB);
            const float  nB = __uint_as_float((uint32)(pB >> 32));
            const u32x4  xB = ((const u32x4*)(xq + (size_t)(uint32)(pB & 0xffffffffu) * IN_CH))[ql];
            const uint32 eB = __builtin_nontemporal_load(eaq + (size_t)sB * 16 + ql);
            #pragma unroll
            for (int j = 0; j < 4; ++j) {
                ax[2*j]   = fmaf(nB, __uint_as_float(xB[j] << 16),         ax[2*j]);
                ax[2*j+1] = fmaf(nB, __uint_as_float(xB[j] & 0xffff0000u), ax[2*j+1]);
            }
            ae0 += __uint_as_float(eB << 16);
            ae1 += __uint_as_float(eB & 0xffff0000u);
        }
    }

    // reduce across the 4 quarters
    #pragma unroll
    for (int j = 0; j < 8; ++j) {
        ax[j] += __shfl_xor(ax[j], 16, 64);
        ax[j] += __shfl_xor(ax[j], 32, 64);
    }
    ae0 += __shfl_xor(ae0, 16, 64); ae0 += __shfl_xor(ae0, 32, 64);
    ae1 += __shfl_xor(ae1, 16, 64); ae1 += __shfl_xor(ae1, 32, 64);

    if (lane < 16) {
        const f32x4 v0 = {ax[0], ax[1], ax[2], ax[3]};
        const f32x4 v1 = {ax[4], ax[5], ax[6], ax[7]};
        ((f32x4*)aggS[w])[2 * ql]     = v0;
        ((f32x4*)aggS[w])[2 * ql + 1] = v1;
        aggS[w][IN_CH + 2 * ql]       = ae0;
        aggS[w][IN_CH + 2 * ql + 1]   = ae1;
    }
    __syncthreads();

    // epilogue: wave w covers k in [40w, 40w+40) for all 4 nodes
    f32x2 pacc[4] = {{0.f, 0.f}, {0.f, 0.f}, {0.f, 0.f}, {0.f, 0.f}};
    const int k0 = 40 * w;
    for (int k = k0; k < k0 + 40; ++k) {
        const f32x2 wv = ((const f32x2*)(W + k * OUT_CH))[lane];
        #pragma unroll
        for (int m = 0; m < 4; ++m) {
            const float av = aggS[m][k];
            pacc[m].x = fmaf(av, wv.x, pacc[m].x);
            pacc[m].y = fmaf(av, wv.y, pacc[m].y);
        }
    }
    #pragma unroll
    for (int m = 0; m < 4; ++m) part[w][m][lane] = pacc[m];
    __syncthreads();

    const int m = w;
    f32x2 o = ((const f32x2*)b)[lane];
    #pragma unroll
    for (int w2 = 0; w2 < 4; ++w2) o += part[w2][m][lane];
    ((f32x2*)(out + (size_t)(blockIdx.x * 4 + m) * OUT_CH))[lane] = o;
}

// ---------------------------------------------------------------------------
// Tier B fallback (ws too small): round-3 proven kernels.
// ---------------------------------------------------------------------------
__global__ __launch_bounds__(256) void csr_build_b_kernel(
    const int* __restrict__ row, const int* __restrict__ col,
    const float* __restrict__ norm, int* __restrict__ ptr, i32x4* __restrict__ csr)
{
    const int e = blockIdx.x * 256 + threadIdx.x;
    if (e >= N_EDGES) return;
    const int r   = row[e];
    const int pos = atomicAdd(&ptr[r], 1);
    i32x4 p;
    p.x = col[e]; p.y = __float_as_int(norm[e]); p.z = e; p.w = 0;
    csr[pos] = p;
}

__global__ __launch_bounds__(256) void gather_gemm_b_kernel(
    const float* __restrict__ x, const float* __restrict__ ea,
    const int* __restrict__ ptr, const i32x4* __restrict__ csr,
    const float* __restrict__ W, const float* __restrict__ b,
    float* __restrict__ out)
{
    __shared__ float aggS[4][AGG_DIM];
    const int w    = threadIdx.x >> 6;
    const int lane = threadIdx.x & 63;
    const int half = lane >> 5;
    const int hl   = lane & 31;
    const int n    = blockIdx.x * 4 + w;

    const int start = (n > 0) ? ptr[n - 1] : 0;
    const int end   = ptr[n];

    f32x4 accx = {0.f, 0.f, 0.f, 0.f};
    f32x4 acce = {0.f, 0.f, 0.f, 0.f};

    int e = start;
    for (; e + 4 <= end; e += 4) {
        const i32x4 pA = __builtin_nontemporal_load(&csr[e + half]);
        const i32x4 pB = __builtin_nontemporal_load(&csr[e + 2 + half]);
        const float nA = __int_as_float(pA.y);
        const float nB = __int_as_float(pB.y);
        const f32x4 xA = ((const f32x4*)(x + (size_t)pA.x * IN_CH))[hl];
        const f32x4 xB = ((const f32x4*)(x + (size_t)pB.x * IN_CH))[hl];
        accx += nA * xA;
        accx += nB * xB;
        if (hl < 8) {
            const f32x4 eA = __builtin_nontemporal_load((const f32x4*)(ea + (size_t)pA.z * EDGE_DIM) + hl);
            const f32x4 eB = __builtin_nontemporal_load((const f32x4*)(ea + (size_t)pB.z * EDGE_DIM) + hl);
            acce += nA * eA;
            acce += nB * eB;
        }
    }
    for (; e < end; e += 2) {
        const int eA = e + half;
        if (eA < end) {
            const i32x4 pA = __builtin_nontemporal_load(&csr[eA]);
            const float nA = __int_as_float(pA.y);
            const f32x4 xA = ((const f32x4*)(x + (size_t)pA.x * IN_CH))[hl];
            accx += nA * xA;
            if (hl < 8) {
                const f32x4 eAv = __builtin_nontemporal_load((const f32x4*)(ea + (size_t)pA.z * EDGE_DIM) + hl);
                acce += nA * eAv;
            }
        }
    }
    #pragma unroll
    for (int i = 0; i < 4; ++i) {
        accx[i] += __shfl_xor(accx[i], 32, 64);
        acce[i] += __shfl_xor(acce[i], 32, 64);
    }
    if (half == 0) {
        ((f32x4*)aggS[w])[hl] = accx;
        if (hl < 8) ((f32x4*)(aggS[w] + IN_CH))[hl] = acce;
    }
    __syncthreads();

    f32x2 acc = ((const f32x2*)b)[lane];
    #pragma unroll 8
    for (int k = 0; k < AGG_DIM; ++k) {
        const float av = aggS[w][k];
        const f32x2 wv = ((const f32x2*)(W + k * OUT_CH))[lane];
        acc.x += av * wv.x;
        acc.y += av * wv.y;
    }
    ((f32x2*)(out + (size_t)n * OUT_CH))[lane] = acc;
}

extern "C" void kernel_launch(void* const* d_in, const int* in_sizes, int n_in,
                              void* d_out, int out_size, void* d_ws, size_t ws_size,
                              hipStream_t stream)
{
    const float* x    = (const float*)d_in[0];
    const int*   row  = (const int*)  d_in[1];
    const int*   col  = (const int*)  d_in[2];
    const float* norm = (const float*)d_in[3];
    const float* ea   = (const float*)d_in[4];
    const float* W    = (const float*)d_in[5];
    const float* b    = (const float*)d_in[6];
    float*       out  = (float*)d_out;

    char* ws     = (char*)d_ws;
    int*  counts = (int*)(ws);
    int*  ptr    = (int*)(ws + (256 << 10));
    int*  bsums  = (int*)(ws + (512 << 10));
    int*  boff   = (int*)(ws + (768 << 10));

    (void)hipMemsetAsync(counts, 0, (size_t)N_NODES * sizeof(int), stream);
    hist_kernel<<<(N_EDGES + 255) / 256, 256, 0, stream>>>(row, counts);
    scan_local_kernel<<<NBLK, SCAN_BS, 0, stream>>>(counts, ptr, bsums);
    scan_sums_kernel<<<1, 64, 0, stream>>>(bsums, boff);
    scan_add_kernel<<<(N_NODES + 255) / 256, 256, 0, stream>>>(ptr, boff);

    if (ws_size >= (140ull << 20)) {
        // Tier A layout: csr64 @1M (12.8 MB), x_bf16 @14M (12.8 MB),
        // csr_ea @27M (102.4 MB) -> ~129.4 MB total.
        uint64*   csr = (uint64*)  (ws + (1ull  << 20));
        ushort16* xq  = (ushort16*)(ws + (14ull << 20));
        u32x4*    eaq = (u32x4*)   (ws + (27ull << 20));

        cvt_x_kernel<<<(N_NODES * IN_CH / 4) / 256, 256, 0, stream>>>(x, xq);
        csr_build_a_kernel<<<(N_EDGES + 255) / 256, 256, 0, stream>>>(
            row, col, norm, ea, ptr, csr, eaq);
        gather_gemm_a_kernel<<<N_NODES / 4, 256, 0, stream>>>(
            xq, csr, (const uint32*)eaq, ptr, W, b, out);
    } else {
        // Tier B layout: csr16 @1M (25.6 MB) -> ~26.6 MB total.
        i32x4* csr = (i32x4*)(ws + (1ull << 20));
        csr_build_b_kernel<<<(N_EDGES + 255) / 256, 256, 0, stream>>>(
            row, col, norm, ptr, csr);
        gather_gemm_b_kernel<<<N_NODES / 4, 256, 0, stream>>>(
            x, ea, ptr, csr, W, b, out);
    }
}